// Round 14
// baseline (348.807 us; speedup 1.0000x reference)
//
#include <hip/hip_runtime.h>
#include <hip/hip_cooperative_groups.h>
#include <math.h>

namespace cg = cooperative_groups;

#define SLOPE  0.2f
#define NB     32
#define LEN    512
#define LATENT 64
#define HID    64
#define IN_DIM 129
#define TROWS  514
#define NTOT   (NB * LEN)      // 16384

typedef __attribute__((ext_vector_type(8)))  short bf16x8;
typedef __attribute__((ext_vector_type(16))) float f32x16;
typedef __attribute__((ext_vector_type(4)))  float f32x4;

struct alignas(8)  US4 { unsigned short x, y, z, w; };
struct alignas(16) US8 { unsigned short s[8]; };

// round-to-nearest bf16 split: v = hi + lo + O(2^-18 v)
__device__ inline void bsplit(float v, unsigned short& hi, unsigned short& lo) {
    unsigned int u  = __builtin_bit_cast(unsigned int, v);
    unsigned int hb = (u + 0x7fffu + ((u >> 16) & 1u)) >> 16;
    hi = (unsigned short)hb;
    float fh = __builtin_bit_cast(float, hb << 16);
    float r  = v - fh;                      // exact (Sterbenz)
    unsigned int u2 = __builtin_bit_cast(unsigned int, r);
    lo = (unsigned short)((u2 + 0x7fffu + ((u2 >> 16) & 1u)) >> 16);
}

// ONE kernel, three modes:
//   phase 2 (cooperative): conv -> grid.sync -> compute
//   phase 0 (fallback)   : conv only
//   phase 1 (fallback)   : compute only
// conv: W1f[l][i][ks][part][lane][8] write-coalesced (R12/R13-validated layout),
//       W1t, out_lad zero. compute: R11 body verbatim (proven 91.6us, VGPR 64).
__global__ __launch_bounds__(256, 4)
void fused_all(const float* xg, const float* W1g, const float* b1g,
               const float* W2g, const float* b2g,
               unsigned short* W1f, float* W1t,
               float* out_res, float* out_lad, int phase)
{
    __shared__ unsigned short sXh[34][72];   // x hi, stride 144B
    __shared__ unsigned short sXl[34][72];   // x lo
    __shared__ float sJ[32][4];              // per-wn partial logsums

    const int tid = threadIdx.x;

    if (phase != 1) {   // ---- conversion phase ----
        const int t = blockIdx.x * 256 + tid;        // 0..262143
        if (t < NTOT) out_lad[t] = 0.f;
        if (t < 4096) W1t[t] = W1g[(size_t)t * IN_DIM + 128];
        if (t < 131072) {
            const int lane = t & 63;
            const int part = (t >> 6) & 1;
            const int ks   = (t >> 7) & 7;
            const int i    = (t >> 10) & 1;
            const int l    = t >> 11;                // 0..63
            const int hi32 = lane >> 5, r32 = lane & 31;
            const int row  = l * 64 + i * 32 + r32;  // <= 4095
            const int k0   = ks * 16 + hi32 * 8;     // <= 120
            const float* src = W1g + (size_t)row * IN_DIM + k0;
            US8 v;
            #pragma unroll
            for (int e = 0; e < 8; ++e) {
                unsigned short h, lo;
                bsplit(src[e], h, lo);
                v.s[e] = part ? lo : h;
            }
            *reinterpret_cast<US8*>(W1f + (size_t)t * 8) = v;
        }
    }

    if (phase == 2) {
        __threadfence();            // device-scope: publish W1f across XCDs
        cg::this_grid().sync();
    }
    if (phase == 0) return;

    // ---- compute phase (R11 body) ----
    const int tile  = blockIdx.x & 511;      // 0..511 : 32-row n-tile
    const int lhalf = blockIdx.x >> 9;       // 0..1   : latent half
    const int pt    = tile >> 4;             // batch row
    const int s     = tile & 15;
    const size_t xrow0 = (size_t)pt * TROWS + s * 32;
    const size_t nbase = (size_t)tile * 32;

    for (int i = tid; i < 34 * 16; i += 256) {
        const int row = i >> 4, c4 = (i & 15) << 2;
        const float4 v = *reinterpret_cast<const float4*>(
            xg + (xrow0 + row) * LATENT + c4);
        unsigned short h0,h1,h2,h3, l0,l1,l2,l3;
        bsplit(v.x, h0, l0); bsplit(v.y, h1, l1);
        bsplit(v.z, h2, l2); bsplit(v.w, h3, l3);
        *reinterpret_cast<US4*>(&sXh[row][c4]) = US4{h0, h1, h2, h3};
        *reinterpret_cast<US4*>(&sXl[row][c4]) = US4{l0, l1, l2, l3};
    }
    __syncthreads();   // single barrier; LDS read-only afterwards

    const int wn   = tid >> 6;               // 0..3
    const int lane = tid & 63;
    const int r32  = lane & 31;
    const int hi32 = lane >> 5;

    float jlog = 0.f, jprod = 1.f;

    #pragma unroll 1
    for (int q = 0; q < 8; ++q) {
        const int l = lhalf * 32 + q * 4 + wn;
        const unsigned short* A0 = W1f + (size_t)l * 16384 + (size_t)lane * 8;

        f32x16 acc[2];
        #pragma unroll
        for (int i = 0; i < 2; ++i)
            #pragma unroll
            for (int r = 0; r < 16; ++r) acc[i][r] = 0.f;

        #pragma unroll
        for (int ks = 0; ks < 8; ++ks) {
            const int lag = ks >> 2;
            const int cc  = (ks & 3) * 16 + hi32 * 8;
            const unsigned short* p0 = A0 + ks * 1024;
            bf16x8 awh[2], awl[2];
            #pragma unroll
            for (int i = 0; i < 2; ++i) {
                awh[i] = *reinterpret_cast<const bf16x8*>(p0 + i * 8192);
                awl[i] = *reinterpret_cast<const bf16x8*>(p0 + i * 8192 + 512);
            }
            const bf16x8 bxh = *reinterpret_cast<const bf16x8*>(&sXh[r32 + lag][cc]);
            const bf16x8 bxl = *reinterpret_cast<const bf16x8*>(&sXl[r32 + lag][cc]);
            #pragma unroll
            for (int i = 0; i < 2; ++i) {
                acc[i] = __builtin_amdgcn_mfma_f32_32x32x16_bf16(awh[i], bxh, acc[i], 0, 0, 0);
                acc[i] = __builtin_amdgcn_mfma_f32_32x32x16_bf16(awh[i], bxl, acc[i], 0, 0, 0);
                acc[i] = __builtin_amdgcn_mfma_f32_32x32x16_bf16(awl[i], bxh, acc[i], 0, 0, 0);
            }
        }

        const float xt0 = xg[(xrow0 + 2 + r32) * LATENT + l];
        float res0 = 0.f, jp0 = 0.f, jc = 0.f;
        #pragma unroll
        for (int i = 0; i < 2; ++i)
            #pragma unroll
            for (int g = 0; g < 4; ++g) {
                const int h0 = l * HID + i * 32 + hi32 * 4 + g * 8;
                const f32x4 wt = *reinterpret_cast<const f32x4*>(W1t + h0);
                const f32x4 w2 = *reinterpret_cast<const f32x4*>(W2g + h0);
                const f32x4 b1 = *reinterpret_cast<const f32x4*>(b1g + h0);
                #pragma unroll
                for (int m = 0; m < 4; ++m) {
                    const float c0 = w2[m] * wt[m];
                    jc += c0;
                    const float pre0 = fmaf(xt0, wt[m], acc[i][g * 4 + m] + b1[m]);
                    res0 += w2[m] * fmaxf(pre0, SLOPE * pre0);
                    jp0 += (pre0 >= 0.f) ? c0 : 0.f;
                }
            }

        res0 += __shfl_xor(res0, 32);
        jp0  += __shfl_xor(jp0, 32);
        jc   += __shfl_xor(jc, 32);
        const float jac = SLOPE * jc + (1.f - SLOPE) * jp0;

        if (hi32 == 0)
            out_res[(nbase + r32) * LATENT + l] = res0 + b2g[l];

        jprod *= jac;
        if ((q & 3) == 3) {              // log every 4 quads (underflow-safe)
            jlog += logf(fabsf(jprod));
            jprod = 1.f;
        }
    }

    if (hi32 == 0) sJ[r32][wn] = jlog;
    __syncthreads();
    if (tid < 32) {
        const float part = sJ[tid][0] + sJ[tid][1] + sJ[tid][2] + sJ[tid][3];
        atomicAdd(&out_lad[nbase + tid], part);
    }
}

extern "C" void kernel_launch(void* const* d_in, const int* in_sizes, int n_in,
                              void* d_out, int out_size, void* d_ws, size_t ws_size,
                              hipStream_t stream) {
    const float* xg  = (const float*)d_in[0];
    const float* W1g = (const float*)d_in[1];
    const float* b1g = (const float*)d_in[2];
    const float* W2g = (const float*)d_in[3];
    const float* b2g = (const float*)d_in[4];

    float* out_res = (float*)d_out;
    float* out_lad = out_res + (size_t)NTOT * LATENT;

    float*          W1t = (float*)d_ws;                   // 16 KB
    unsigned short* W1f = (unsigned short*)(W1t + 4096);  // 2 MB fragment-major

    int phase2 = 2;
    void* args[] = { (void*)&xg, (void*)&W1g, (void*)&b1g, (void*)&W2g,
                     (void*)&b2g, (void*)&W1f, (void*)&W1t,
                     (void*)&out_res, (void*)&out_lad, (void*)&phase2 };

    // 1024 blocks x 256 thr = exactly 4 blocks/CU co-resident (LDS 10.8KB, VGPR~64)
    hipError_t err = hipLaunchCooperativeKernel((const void*)fused_all,
                                                dim3(1024), dim3(256),
                                                args, 0, stream);
    if (err != hipSuccess) {
        // fallback: two regular launches (== proven R11 behavior)
        fused_all<<<1024, 256, 0, stream>>>(xg, W1g, b1g, W2g, b2g,
                                            W1f, W1t, out_res, out_lad, 0);
        fused_all<<<1024, 256, 0, stream>>>(xg, W1g, b1g, W2g, b2g,
                                            W1f, W1t, out_res, out_lad, 1);
    }
}